// Round 13
// baseline (63.919 us; speedup 1.0000x reference)
//
#include <hip/hip_runtime.h>

typedef __attribute__((ext_vector_type(8)))  short    short8;   // 8 bf16 (K=32 A/B frag)
typedef __attribute__((ext_vector_type(4)))  short    s16x4;    // 4 bf16 (K=16 A/B frag)
typedef __attribute__((ext_vector_type(4)))  float    f32x4;    // 16x16 C/D frag
typedef __attribute__((ext_vector_type(4)))  unsigned uint4_;
typedef __attribute__((ext_vector_type(2)))  unsigned uint2_;

#define HW     16000
#define WWID   200
#define NPARAM 8513
#define REP    4   // DIAGNOSTIC: dur = pack + P + REP*L; idempotent re-stores
// raw param offsets: w0[64][66] @0, w1[64][64] @4224, w2 @8320, b0 @8384, b1 @8448, b2 @8512
// packed ws per instance (dwords, stride 6144 = 24KB):
//   w0 K=32 A-frags [0,3072): 12 frags (ch*4+kb) x 256 dw; lane*4+d
//   w1 K=16 A-frags [3072,5120): 16 frags (kb*4+ks) x 128 dw; lane*2+d
//   b1 f32 @5120(64), w2 f32 @5184(64), b2 @5248
#define PACK_STRIDE 6144

__device__ __forceinline__ unsigned pkbf2(float a, float b) {   // 1 VALU op (RNE)
    unsigned r;
    asm("v_cvt_pk_bf16_f32 %0, %1, %2" : "=v"(r) : "v"(a), "v"(b));
    return r;
}
__device__ __forceinline__ s16x4 mk4(unsigned a, unsigned b) {
    uint2_ u; u.x = a; u.y = b;
    return __builtin_bit_cast(s16x4, u);
}
// K=16 bf16 MFMA via inline asm; leading s_nop 2 covers the VALU-write ->
// MFMA-read wait states the compiler can't insert through asm (R10 lesson).
__device__ __forceinline__ void mfma16(f32x4& acc, s16x4 a, s16x4 b) {
    asm("s_nop 2\n\tv_mfma_f32_16x16x16_bf16 %0, %1, %2, %0"
        : "+v"(acc) : "v"(a), "v"(b));
}

// L0 K-channel map: 0..63 -> x (w0 col c+2); 64 -> lx (col 0); 65 -> ly (col 1);
// 66 -> 1*b0; 67..95 -> 0
__device__ __forceinline__ float w0val(const float* pm, int k, int c) {
    if (c < 64)  return pm[k * 66 + c + 2];
    if (c == 64) return pm[k * 66 + 0];
    if (c == 65) return pm[k * 66 + 1];
    if (c == 66) return pm[8384 + k];
    return 0.0f;
}

// grid (M, 2) x 256 thr. y=0: w0 frags + smalls (R4-verified layout); y=1: w1 K=16 frags.
__global__ __launch_bounds__(256) void pack_weights(
    const float* __restrict__ params, unsigned* __restrict__ wp)
{
    const int m   = blockIdx.x;
    const int tid = threadIdx.x;
    const float* pm = params + (size_t)m * NPARAM;
    unsigned* dst = wp + (size_t)m * PACK_STRIDE;

    if (blockIdx.y == 0) {
        const int l  = tid >> 2;
        const int i0 = (tid & 3) * 2;
        #pragma unroll
        for (int frag = 0; frag < 12; ++frag) {        // w0, K=96 (ch*4+kb)
            int ch = frag >> 2, kb = frag & 3;
            int k = kb * 16 + (l & 15);
            int c = ch * 32 + (l >> 4) * 8 + i0;
            dst[frag * 256 + tid] = pkbf2(w0val(pm, k, c), w0val(pm, k, c + 1));
        }
        float* fd = (float*)dst;
        if (tid < 64) {
            fd[5120 + tid] = pm[8448 + tid];           // b1
            fd[5184 + tid] = pm[8320 + tid];           // w2
        }
        if (tid == 0) fd[5248] = pm[8512];             // b2
    } else {
        #pragma unroll
        for (int i = tid; i < 2048; i += 256) {        // w1 K=16 A-frags
            int f = i >> 7, r = i & 127;
            int l = r >> 1, d = i & 1;
            int kb = f >> 2, ks = f & 3;
            int row = kb * 16 + (l & 15);
            int col = ks * 16 + (l >> 4) * 4 + d * 2;
            const float* s = pm + 4224 + row * 64 + col;
            dst[3072 + i] = pkbf2(s[0], s[1]);
        }
    }
}

// block = 512 thr (8 waves); wave wid owns FULL instance m = n*num_ins+wid.
// R12 structure exactly; slice loop wrapped in REP for P/L decomposition.
__global__ __launch_bounds__(512, 3) void condlane_reg(
    const float* __restrict__ x,        // [N, 64, HW]
    const unsigned* __restrict__ wp,    // packed weights
    float* __restrict__ out,            // [M, HW]
    int num_ins)
{
    extern __shared__ char lds_[];
    char* xt = lds_;                    // 65536 B
    const int tid  = threadIdx.x;
    const int lane = tid & 63;
    const int wid  = tid >> 6;
    const int n    = blockIdx.y;
    const int pxg0 = blockIdx.x * 256;
    const int g    = (lane >> 4) & 3;
    const int px16 = lane & 15;

    // ---- stage x tile: [256 px][128 ch] bf16, swizzle byte ^= (p&15)<<4 ----
    {
        const int p   = tid & 255;
        const int sel = tid >> 8;       // 0..1, 32 fp32 channels each
        const int pc  = min(pxg0 + p, HW - 1);
        const float* xp = x + (size_t)n * 64 * HW + pc;
        #pragma unroll
        for (int it = 0; it < 4; ++it) {
            int c0 = sel * 32 + it * 8;
            uint4_ d;
            d.x = pkbf2(xp[(size_t)(c0 + 0) * HW], xp[(size_t)(c0 + 1) * HW]);
            d.y = pkbf2(xp[(size_t)(c0 + 2) * HW], xp[(size_t)(c0 + 3) * HW]);
            d.z = pkbf2(xp[(size_t)(c0 + 4) * HW], xp[(size_t)(c0 + 5) * HW]);
            d.w = pkbf2(xp[(size_t)(c0 + 6) * HW], xp[(size_t)(c0 + 7) * HW]);
            *(uint4_*)(xt + ((p * 256 + c0 * 2) ^ ((p & 15) << 4))) = d;
        }
        // const K-channels 64..95 = {lx, ly, 1, 0 ...}
        const int pg = pxg0 + p;        // values for pg>=HW never consumed
        float lx = (float)(pg % WWID) * (1.0f / WWID);
        float ly = (float)(pg / WWID) * (1.0f / WWID);   // source bug: also /W
        uint4_ z;  z.x = 0; z.y = 0; z.z = 0; z.w = 0;
        uint4_ cv; cv.x = pkbf2(lx, ly); cv.y = pkbf2(1.f, 0.f); cv.z = 0; cv.w = 0;
        int ba = (p * 256 + 128 + sel * 32) ^ ((p & 15) << 4);
        int bb = (p * 256 + 144 + sel * 32) ^ ((p & 15) << 4);
        *(uint4_*)(xt + ba) = (sel == 0) ? cv : z;
        *(uint4_*)(xt + bb) = z;
    }

    // ---- wave-resident weights: coalesced loads from packed image ----
    const int m = n * num_ins + wid;    // 8 waves == num_ins
    const unsigned* wm = wp + (size_t)m * PACK_STRIDE;

    short8 w0f[3][4];
    s16x4  w1f4[4][4];
    #pragma unroll
    for (int ch = 0; ch < 3; ++ch)
        #pragma unroll
        for (int kb = 0; kb < 4; ++kb)
            w0f[ch][kb] = *(const short8*)(wm + (ch * 4 + kb) * 256 + lane * 4);
    #pragma unroll
    for (int kb = 0; kb < 4; ++kb)
        #pragma unroll
        for (int ks = 0; ks < 4; ++ks)
            w1f4[kb][ks] = *(const s16x4*)(wm + 3072 + (kb * 4 + ks) * 128 + lane * 2);
    const float* fm = (const float*)wm;
    f32x4 bias1[4], w2v[4];
    #pragma unroll
    for (int kb = 0; kb < 4; ++kb) {
        bias1[kb] = *(const f32x4*)(fm + 5120 + kb * 16 + g * 4);
        w2v[kb]   = *(const f32x4*)(fm + 5184 + kb * 16 + g * 4);
    }
    const float b2 = fm[5248] - 2.19f;

    __syncthreads();                    // xt ready — the only barrier

    const int swz = px16 << 4;
    const int nsl = min(16, (HW - pxg0) >> 4);

    #pragma unroll 1
    for (int rep = 0; rep < REP; ++rep) {
        for (int s = 0; s < 16; ++s) {
            const int pxl = s * 16 + px16;
            short8 xf[3];
            #pragma unroll
            for (int ch = 0; ch < 3; ++ch)
                xf[ch] = *(const short8*)(xt + ((pxl * 256 + ch * 64 + g * 16) ^ swz));
            // layer 0: 12 MFMA (K=96), acc = 0 (loc+bias folded)
            f32x4 acc0[4];
            #pragma unroll
            for (int kb = 0; kb < 4; ++kb)
                #pragma unroll
                for (int j = 0; j < 4; ++j) acc0[kb][j] = 0.f;
            #pragma unroll
            for (int ch = 0; ch < 3; ++ch)
                #pragma unroll
                for (int kb = 0; kb < 4; ++kb)
                    acc0[kb] = __builtin_amdgcn_mfma_f32_16x16x32_bf16(w0f[ch][kb], xf[ch], acc0[kb], 0, 0, 0);
            // relu -> bf16 in registers: acc0[ks] becomes L1's B-frag for chunk ks
            s16x4 hf[4];
            #pragma unroll
            for (int ks = 0; ks < 4; ++ks)
                hf[ks] = mk4(pkbf2(fmaxf(acc0[ks][0], 0.f), fmaxf(acc0[ks][1], 0.f)),
                             pkbf2(fmaxf(acc0[ks][2], 0.f), fmaxf(acc0[ks][3], 0.f)));
            // layer 1: 16 x K=16 MFMA (asm, hazard-protected)
            f32x4 acc1[4];
            #pragma unroll
            for (int kb = 0; kb < 4; ++kb) acc1[kb] = bias1[kb];
            #pragma unroll
            for (int ks = 0; ks < 4; ++ks)
                #pragma unroll
                for (int kb = 0; kb < 4; ++kb)
                    mfma16(acc1[kb], w1f4[kb][ks], hf[ks]);
            // exit hazard: MFMA write -> VALU read (nops tied to accs for ordering)
            asm("s_nop 7\n\ts_nop 7"
                : "+v"(acc1[0]), "+v"(acc1[1]), "+v"(acc1[2]), "+v"(acc1[3]));
            // layer 2: 64->1 fp32 VALU + cross-group reduce
            float v = 0.f;
            #pragma unroll
            for (int kb = 0; kb < 4; ++kb)
                #pragma unroll
                for (int r = 0; r < 4; ++r)
                    v += w2v[kb][r] * fmaxf(acc1[kb][r], 0.f);
            v += __shfl_xor(v, 16);
            v += __shfl_xor(v, 32);
            if (lane < 16 && s < nsl)
                out[(size_t)m * HW + pxg0 + s * 16 + lane] = v + b2;
        }
        // prevent cross-rep store elimination / hoisting; regs are unaffected
        asm volatile("" ::: "memory");
    }
}

extern "C" void kernel_launch(void* const* d_in, const int* in_sizes, int n_in,
                              void* d_out, int out_size, void* d_ws, size_t ws_size,
                              hipStream_t stream) {
    const float* x      = (const float*)d_in[0];
    const float* params = (const float*)d_in[1];
    float* out          = (float*)d_out;

    const int N = in_sizes[0] / (64 * HW);   // 4
    const int M = in_sizes[1] / NPARAM;      // 32
    const int num_ins = M / N;               // 8

    pack_weights<<<dim3(M, 2), 256, 0, stream>>>(params, (unsigned*)d_ws);

    dim3 grid((HW + 255) / 256, N);          // 63 x 4 = 252 blocks
    condlane_reg<<<grid, 512, 65536, stream>>>(x, (const unsigned*)d_ws, out, num_ins);
}

// Round 14
// 58.380 us; speedup vs baseline: 1.0949x; 1.0949x over previous
//
#include <hip/hip_runtime.h>

typedef __attribute__((ext_vector_type(8)))  short    short8;   // 8 bf16 (K=32 A/B frag)
typedef __attribute__((ext_vector_type(4)))  short    s16x4;    // 4 bf16 (K=16 A/B frag)
typedef __attribute__((ext_vector_type(4)))  float    f32x4;    // 16x16 C/D frag
typedef __attribute__((ext_vector_type(4)))  unsigned uint4_;
typedef __attribute__((ext_vector_type(2)))  unsigned uint2_;

#define HW     16000
#define WWID   200
#define NPARAM 8513
// raw param offsets: w0[64][66] @0, w1[64][64] @4224, w2 @8320, b0 @8384, b1 @8448, b2 @8512
// packed ws per instance (dwords, stride 6144 = 24KB):
//   w0 K=32 A-frags [0,3072): 12 frags (ch*4+kb) x 256 dw; lane*4+d
//   w1 K=16 A-frags [3072,5120): 16 frags (kb*4+ks) x 128 dw; lane*2+d
//   b1 f32 @5120(64), w2 f32 @5184(64), b2 @5248
#define PACK_STRIDE 6144

__device__ __forceinline__ unsigned pkbf2(float a, float b) {   // 1 VALU op (RNE)
    unsigned r;
    asm("v_cvt_pk_bf16_f32 %0, %1, %2" : "=v"(r) : "v"(a), "v"(b));
    return r;
}
__device__ __forceinline__ s16x4 mk4(unsigned a, unsigned b) {
    uint2_ u; u.x = a; u.y = b;
    return __builtin_bit_cast(s16x4, u);
}
// K=16 bf16 MFMA via inline asm; leading s_nop 2 covers the VALU-write ->
// MFMA-read wait states the compiler can't insert through asm (R10 lesson).
__device__ __forceinline__ void mfma16(f32x4& acc, s16x4 a, s16x4 b) {
    asm("s_nop 2\n\tv_mfma_f32_16x16x16_bf16 %0, %1, %2, %0"
        : "+v"(acc) : "v"(a), "v"(b));
}

// L0 K-channel map: 0..63 -> x (w0 col c+2); 64 -> lx (col 0); 65 -> ly (col 1);
// 66 -> 1*b0; 67..95 -> 0
__device__ __forceinline__ float w0val(const float* pm, int k, int c) {
    if (c < 64)  return pm[k * 66 + c + 2];
    if (c == 64) return pm[k * 66 + 0];
    if (c == 65) return pm[k * 66 + 1];
    if (c == 66) return pm[8384 + k];
    return 0.0f;
}

// grid (M, 2) x 256 thr. y=0: w0 frags + smalls; y=1: w1 K=16 frags.
__global__ __launch_bounds__(256) void pack_weights(
    const float* __restrict__ params, unsigned* __restrict__ wp)
{
    const int m   = blockIdx.x;
    const int tid = threadIdx.x;
    const float* pm = params + (size_t)m * NPARAM;
    unsigned* dst = wp + (size_t)m * PACK_STRIDE;

    if (blockIdx.y == 0) {
        const int l  = tid >> 2;
        const int i0 = (tid & 3) * 2;
        #pragma unroll
        for (int frag = 0; frag < 12; ++frag) {        // w0, K=96 (ch*4+kb)
            int ch = frag >> 2, kb = frag & 3;
            int k = kb * 16 + (l & 15);
            int c = ch * 32 + (l >> 4) * 8 + i0;
            dst[frag * 256 + tid] = pkbf2(w0val(pm, k, c), w0val(pm, k, c + 1));
        }
        float* fd = (float*)dst;
        if (tid < 64) {
            fd[5120 + tid] = pm[8448 + tid];           // b1
            fd[5184 + tid] = pm[8320 + tid];           // w2
        }
        if (tid == 0) fd[5248] = pm[8512];             // b2
    } else {
        #pragma unroll
        for (int i = tid; i < 2048; i += 256) {        // w1 K=16 A-frags
            int f = i >> 7, r = i & 127;
            int l = r >> 1, d = i & 1;
            int kb = f >> 2, ks = f & 3;
            int row = kb * 16 + (l & 15);
            int col = ks * 16 + (l >> 4) * 4 + d * 2;
            const float* s = pm + 4224 + row * 64 + col;
            dst[3072 + i] = pkbf2(s[0], s[1]);
        }
    }
}

// block = 512 thr (8 waves); wave wid owns FULL instance m = n*num_ins+wid over
// a 128-px tile (8 slices). Grid 125 x N = 500 blocks -> ~2 blocks/CU: 4 waves/
// SIMD and cross-block P/L overlap (R13 showed occupancy was grid-capped).
// Loop identical to R12: relu(acc0) in regs IS L1's B operand; no in-loop
// barriers/LDS. LDS: xt [128 px][128 ch] bf16 swizzled = 32 KB.
__global__ __launch_bounds__(512, 4) void condlane_reg(
    const float* __restrict__ x,        // [N, 64, HW]
    const unsigned* __restrict__ wp,    // packed weights
    float* __restrict__ out,            // [M, HW]
    int num_ins)
{
    extern __shared__ char lds_[];
    char* xt = lds_;                    // 32768 B
    const int tid  = threadIdx.x;
    const int lane = tid & 63;
    const int wid  = tid >> 6;
    const int n    = blockIdx.y;
    const int pxg0 = blockIdx.x * 128;  // 125*128 == HW exactly, no tail
    const int g    = (lane >> 4) & 3;
    const int px16 = lane & 15;

    // ---- stage x tile: [128 px][128 ch] bf16, swizzle byte ^= (p&15)<<4 ----
    {
        const int p   = tid & 127;
        const int sel = tid >> 7;       // 0..3, 16 fp32 channels each
        const float* xp = x + (size_t)n * 64 * HW + (pxg0 + p);
        #pragma unroll
        for (int it = 0; it < 2; ++it) {
            int c0 = sel * 16 + it * 8;
            uint4_ d;
            d.x = pkbf2(xp[(size_t)(c0 + 0) * HW], xp[(size_t)(c0 + 1) * HW]);
            d.y = pkbf2(xp[(size_t)(c0 + 2) * HW], xp[(size_t)(c0 + 3) * HW]);
            d.z = pkbf2(xp[(size_t)(c0 + 4) * HW], xp[(size_t)(c0 + 5) * HW]);
            d.w = pkbf2(xp[(size_t)(c0 + 6) * HW], xp[(size_t)(c0 + 7) * HW]);
            *(uint4_*)(xt + ((p * 256 + c0 * 2) ^ ((p & 15) << 4))) = d;
        }
        // const K-channels 64..95 = {lx, ly, 1, 0 ...}; sel writes 16B at 128+sel*16
        const int pg = pxg0 + p;
        float lx = (float)(pg % WWID) * (1.0f / WWID);
        float ly = (float)(pg / WWID) * (1.0f / WWID);   // source bug: also /W
        uint4_ cv;
        cv.x = (sel == 0) ? pkbf2(lx, ly)   : 0u;
        cv.y = (sel == 0) ? pkbf2(1.f, 0.f) : 0u;
        cv.z = 0u; cv.w = 0u;
        *(uint4_*)(xt + ((p * 256 + 128 + sel * 16) ^ ((p & 15) << 4))) = cv;
    }

    // ---- wave-resident weights: coalesced loads from packed image ----
    const int m = n * num_ins + wid;    // 8 waves == num_ins
    const unsigned* wm = wp + (size_t)m * PACK_STRIDE;

    short8 w0f[3][4];
    s16x4  w1f4[4][4];
    #pragma unroll
    for (int ch = 0; ch < 3; ++ch)
        #pragma unroll
        for (int kb = 0; kb < 4; ++kb)
            w0f[ch][kb] = *(const short8*)(wm + (ch * 4 + kb) * 256 + lane * 4);
    #pragma unroll
    for (int kb = 0; kb < 4; ++kb)
        #pragma unroll
        for (int ks = 0; ks < 4; ++ks)
            w1f4[kb][ks] = *(const s16x4*)(wm + 3072 + (kb * 4 + ks) * 128 + lane * 2);
    const float* fm = (const float*)wm;
    f32x4 bias1[4], w2v[4];
    #pragma unroll
    for (int kb = 0; kb < 4; ++kb) {
        bias1[kb] = *(const f32x4*)(fm + 5120 + kb * 16 + g * 4);
        w2v[kb]   = *(const f32x4*)(fm + 5184 + kb * 16 + g * 4);
    }
    const float b2 = fm[5248] - 2.19f;
    f32x4 zero4; zero4[0] = 0.f; zero4[1] = 0.f; zero4[2] = 0.f; zero4[3] = 0.f;

    __syncthreads();                    // xt ready — the only barrier

    const int swz = px16 << 4;

    for (int s = 0; s < 8; ++s) {
        const int pxl = s * 16 + px16;
        short8 xf[3];
        #pragma unroll
        for (int ch = 0; ch < 3; ++ch)
            xf[ch] = *(const short8*)(xt + ((pxl * 256 + ch * 64 + g * 16) ^ swz));
        // layer 0: 12 MFMA (K=96); first ch initializes from invariant zero
        // (no per-slice acc-zeroing VALU)
        f32x4 acc0[4];
        #pragma unroll
        for (int kb = 0; kb < 4; ++kb)
            acc0[kb] = __builtin_amdgcn_mfma_f32_16x16x32_bf16(w0f[0][kb], xf[0], zero4, 0, 0, 0);
        #pragma unroll
        for (int ch = 1; ch < 3; ++ch)
            #pragma unroll
            for (int kb = 0; kb < 4; ++kb)
                acc0[kb] = __builtin_amdgcn_mfma_f32_16x16x32_bf16(w0f[ch][kb], xf[ch], acc0[kb], 0, 0, 0);
        // relu -> bf16 in registers: acc0[ks] becomes L1's B-frag for chunk ks
        s16x4 hf[4];
        #pragma unroll
        for (int ks = 0; ks < 4; ++ks)
            hf[ks] = mk4(pkbf2(fmaxf(acc0[ks][0], 0.f), fmaxf(acc0[ks][1], 0.f)),
                         pkbf2(fmaxf(acc0[ks][2], 0.f), fmaxf(acc0[ks][3], 0.f)));
        // layer 1: 16 x K=16 MFMA (asm, hazard-protected)
        f32x4 acc1[4];
        #pragma unroll
        for (int kb = 0; kb < 4; ++kb) acc1[kb] = bias1[kb];
        #pragma unroll
        for (int ks = 0; ks < 4; ++ks)
            #pragma unroll
            for (int kb = 0; kb < 4; ++kb)
                mfma16(acc1[kb], w1f4[kb][ks], hf[ks]);
        // exit hazard: MFMA write -> VALU read (nops tied to accs for ordering)
        asm("s_nop 7\n\ts_nop 7"
            : "+v"(acc1[0]), "+v"(acc1[1]), "+v"(acc1[2]), "+v"(acc1[3]));
        // layer 2: 64->1 fp32 VALU + cross-group reduce
        float v = 0.f;
        #pragma unroll
        for (int kb = 0; kb < 4; ++kb)
            #pragma unroll
            for (int r = 0; r < 4; ++r)
                v += w2v[kb][r] * fmaxf(acc1[kb][r], 0.f);
        v += __shfl_xor(v, 16);
        v += __shfl_xor(v, 32);
        if (lane < 16)
            out[(size_t)m * HW + pxg0 + s * 16 + lane] = v + b2;
    }
}

extern "C" void kernel_launch(void* const* d_in, const int* in_sizes, int n_in,
                              void* d_out, int out_size, void* d_ws, size_t ws_size,
                              hipStream_t stream) {
    const float* x      = (const float*)d_in[0];
    const float* params = (const float*)d_in[1];
    float* out          = (float*)d_out;

    const int N = in_sizes[0] / (64 * HW);   // 4
    const int M = in_sizes[1] / NPARAM;      // 32
    const int num_ins = M / N;               // 8

    pack_weights<<<dim3(M, 2), 256, 0, stream>>>(params, (unsigned*)d_ws);

    dim3 grid(HW / 128, N);                  // 125 x 4 = 500 blocks
    condlane_reg<<<grid, 512, 32768, stream>>>(x, (const unsigned*)d_ws, out, num_ins);
}

// Round 15
// 28.781 us; speedup vs baseline: 2.2208x; 2.0284x over previous
//
#include <hip/hip_runtime.h>

typedef __attribute__((ext_vector_type(8)))  short    short8;   // 8 bf16 (K=32 A/B frag)
typedef __attribute__((ext_vector_type(4)))  short    s16x4;    // 4 bf16 (K=16 A/B frag)
typedef __attribute__((ext_vector_type(4)))  float    f32x4;    // 16x16 C/D frag
typedef __attribute__((ext_vector_type(4)))  unsigned uint4_;
typedef __attribute__((ext_vector_type(2)))  unsigned uint2_;

#define HW     16000
#define WWID   200
#define NPARAM 8513
// raw param offsets: w0[64][66] @0, w1[64][64] @4224, w2 @8320, b0 @8384, b1 @8448, b2 @8512
// packed ws per instance (dwords, stride 6144 = 24KB):
//   w0 K=32 A-frags [0,3072): 12 frags (ch*4+kb) x 256 dw; lane*4+d
//   w1 K=16 A-frags [3072,5120): 16 frags (kb*4+ks) x 128 dw; lane*2+d
//   b1 f32 @5120(64), w2 f32 @5184(64), b2 @5248
#define PACK_STRIDE 6144

__device__ __forceinline__ unsigned pkbf2(float a, float b) {   // 1 VALU op (RNE)
    unsigned r;
    asm("v_cvt_pk_bf16_f32 %0, %1, %2" : "=v"(r) : "v"(a), "v"(b));
    return r;
}
__device__ __forceinline__ s16x4 mk4(unsigned a, unsigned b) {
    uint2_ u; u.x = a; u.y = b;
    return __builtin_bit_cast(s16x4, u);
}
// K=16 bf16 MFMA via inline asm; leading s_nop 2 covers the VALU-write ->
// MFMA-read wait states the compiler can't insert through asm (R10 lesson).
__device__ __forceinline__ void mfma16(f32x4& acc, s16x4 a, s16x4 b) {
    asm("s_nop 2\n\tv_mfma_f32_16x16x16_bf16 %0, %1, %2, %0"
        : "+v"(acc) : "v"(a), "v"(b));
}

// L0 K-channel map: 0..63 -> x (w0 col c+2); 64 -> lx (col 0); 65 -> ly (col 1);
// 66 -> 1*b0; 67..95 -> 0
__device__ __forceinline__ float w0val(const float* pm, int k, int c) {
    if (c < 64)  return pm[k * 66 + c + 2];
    if (c == 64) return pm[k * 66 + 0];
    if (c == 65) return pm[k * 66 + 1];
    if (c == 66) return pm[8384 + k];
    return 0.0f;
}

// grid (M, 2) x 256 thr. y=0: w0 frags + smalls; y=1: w1 K=16 frags.
__global__ __launch_bounds__(256) void pack_weights(
    const float* __restrict__ params, unsigned* __restrict__ wp)
{
    const int m   = blockIdx.x;
    const int tid = threadIdx.x;
    const float* pm = params + (size_t)m * NPARAM;
    unsigned* dst = wp + (size_t)m * PACK_STRIDE;

    if (blockIdx.y == 0) {
        const int l  = tid >> 2;
        const int i0 = (tid & 3) * 2;
        #pragma unroll
        for (int frag = 0; frag < 12; ++frag) {        // w0, K=96 (ch*4+kb)
            int ch = frag >> 2, kb = frag & 3;
            int k = kb * 16 + (l & 15);
            int c = ch * 32 + (l >> 4) * 8 + i0;
            dst[frag * 256 + tid] = pkbf2(w0val(pm, k, c), w0val(pm, k, c + 1));
        }
        float* fd = (float*)dst;
        if (tid < 64) {
            fd[5120 + tid] = pm[8448 + tid];           // b1
            fd[5184 + tid] = pm[8320 + tid];           // w2
        }
        if (tid == 0) fd[5248] = pm[8512];             // b2
    } else {
        #pragma unroll
        for (int i = tid; i < 2048; i += 256) {        // w1 K=16 A-frags
            int f = i >> 7, r = i & 127;
            int l = r >> 1, d = i & 1;
            int kb = f >> 2, ks = f & 3;
            int row = kb * 16 + (l & 15);
            int col = ks * 16 + (l >> 4) * 4 + d * 2;
            const float* s = pm + 4224 + row * 64 + col;
            dst[3072 + i] = pkbf2(s[0], s[1]);
        }
    }
}

// block = 512 thr (8 waves); wave wid owns FULL instance m = n*num_ins+wid over
// a 128-px tile (8 slices). Grid 125 x N = 500 blocks -> 2 blocks/CU.
// Register diet vs R13: bias1/w2v/b2 (33 fp32) live in a per-wave LDS region
// (acc1 init = direct ds_read_b128), bringing unified regs to ~125 <= the 128
// occupancy step -> 4 waves/SIMD WITHOUT spill (R14's failure mode).
// LDS: xt 32KB + smalls 8 x 544B = 37120 B (2 blocks = 74KB <= 160KB).
__global__ __launch_bounds__(512, 4) void condlane_reg(
    const float* __restrict__ x,        // [N, 64, HW]
    const unsigned* __restrict__ wp,    // packed weights
    float* __restrict__ out,            // [M, HW]
    int num_ins)
{
    extern __shared__ char lds_[];
    char*  xt = lds_;                   // 32768 B
    float* sm = (float*)(lds_ + 32768); // [8 waves][136 f32]: b1(64), w2(64), b2
    const int tid  = threadIdx.x;
    const int lane = tid & 63;
    const int wid  = tid >> 6;
    const int n    = blockIdx.y;
    const int pxg0 = blockIdx.x * 128;  // 125*128 == HW exactly, no tail
    const int g    = (lane >> 4) & 3;
    const int px16 = lane & 15;

    // ---- stage x tile: [128 px][128 ch] bf16, swizzle byte ^= (p&15)<<4 ----
    {
        const int p   = tid & 127;
        const int sel = tid >> 7;       // 0..3, 16 fp32 channels each
        const float* xp = x + (size_t)n * 64 * HW + (pxg0 + p);
        #pragma unroll
        for (int it = 0; it < 2; ++it) {
            int c0 = sel * 16 + it * 8;
            uint4_ d;
            d.x = pkbf2(xp[(size_t)(c0 + 0) * HW], xp[(size_t)(c0 + 1) * HW]);
            d.y = pkbf2(xp[(size_t)(c0 + 2) * HW], xp[(size_t)(c0 + 3) * HW]);
            d.z = pkbf2(xp[(size_t)(c0 + 4) * HW], xp[(size_t)(c0 + 5) * HW]);
            d.w = pkbf2(xp[(size_t)(c0 + 6) * HW], xp[(size_t)(c0 + 7) * HW]);
            *(uint4_*)(xt + ((p * 256 + c0 * 2) ^ ((p & 15) << 4))) = d;
        }
        // const K-channels 64..95 = {lx, ly, 1, 0 ...}
        const int pg = pxg0 + p;
        float lx = (float)(pg % WWID) * (1.0f / WWID);
        float ly = (float)(pg / WWID) * (1.0f / WWID);   // source bug: also /W
        uint4_ cv;
        cv.x = (sel == 0) ? pkbf2(lx, ly)   : 0u;
        cv.y = (sel == 0) ? pkbf2(1.f, 0.f) : 0u;
        cv.z = 0u; cv.w = 0u;
        *(uint4_*)(xt + ((p * 256 + 128 + sel * 16) ^ ((p & 15) << 4))) = cv;
    }

    // ---- wave-resident weights (coalesced from packed image) + LDS smalls ----
    const int m = n * num_ins + wid;    // 8 waves == num_ins
    const unsigned* wm = wp + (size_t)m * PACK_STRIDE;
    const float*    fm = (const float*)wm;
    float* sw = sm + wid * 136;         // this wave's smalls (wave-private)

    sw[lane]      = fm[5120 + lane];    // b1
    sw[64 + lane] = fm[5184 + lane];    // w2
    if (lane == 0) sw[128] = fm[5248];  // b2

    short8 w0f[3][4];
    s16x4  w1f4[4][4];
    #pragma unroll
    for (int ch = 0; ch < 3; ++ch)
        #pragma unroll
        for (int kb = 0; kb < 4; ++kb)
            w0f[ch][kb] = *(const short8*)(wm + (ch * 4 + kb) * 256 + lane * 4);
    #pragma unroll
    for (int kb = 0; kb < 4; ++kb)
        #pragma unroll
        for (int ks = 0; ks < 4; ++ks)
            w1f4[kb][ks] = *(const s16x4*)(wm + 3072 + (kb * 4 + ks) * 128 + lane * 2);

    __syncthreads();                    // xt ready — the only barrier

    const int swz = px16 << 4;
    const float* swg = sw + g * 4;      // lane's bias/w2 base (b1 @0, w2 @64)

    for (int s = 0; s < 8; ++s) {
        const int pxl = s * 16 + px16;
        short8 xf[3];
        #pragma unroll
        for (int ch = 0; ch < 3; ++ch)
            xf[ch] = *(const short8*)(xt + ((pxl * 256 + ch * 64 + g * 16) ^ swz));
        // layer 0: 12 MFMA (K=96); first ch initializes from zero C
        f32x4 zero4; zero4[0] = 0.f; zero4[1] = 0.f; zero4[2] = 0.f; zero4[3] = 0.f;
        f32x4 acc0[4];
        #pragma unroll
        for (int kb = 0; kb < 4; ++kb)
            acc0[kb] = __builtin_amdgcn_mfma_f32_16x16x32_bf16(w0f[0][kb], xf[0], zero4, 0, 0, 0);
        #pragma unroll
        for (int ch = 1; ch < 3; ++ch)
            #pragma unroll
            for (int kb = 0; kb < 4; ++kb)
                acc0[kb] = __builtin_amdgcn_mfma_f32_16x16x32_bf16(w0f[ch][kb], xf[ch], acc0[kb], 0, 0, 0);
        // relu -> bf16 in registers: acc0[ks] becomes L1's B-frag for chunk ks
        s16x4 hf[4];
        #pragma unroll
        for (int ks = 0; ks < 4; ++ks)
            hf[ks] = mk4(pkbf2(fmaxf(acc0[ks][0], 0.f), fmaxf(acc0[ks][1], 0.f)),
                         pkbf2(fmaxf(acc0[ks][2], 0.f), fmaxf(acc0[ks][3], 0.f)));
        // layer 1: acc1 initialized DIRECTLY by ds_read of b1 (no reg-resident bias)
        f32x4 acc1[4];
        #pragma unroll
        for (int kb = 0; kb < 4; ++kb)
            acc1[kb] = *(const f32x4*)(swg + kb * 16);
        #pragma unroll
        for (int ks = 0; ks < 4; ++ks)
            #pragma unroll
            for (int kb = 0; kb < 4; ++kb)
                mfma16(acc1[kb], w1f4[kb][ks], hf[ks]);
        // exit hazard: MFMA write -> VALU read (nops tied to accs for ordering)
        asm("s_nop 7\n\ts_nop 7"
            : "+v"(acc1[0]), "+v"(acc1[1]), "+v"(acc1[2]), "+v"(acc1[3]));
        // layer 2: 64->1 fp32 VALU, w2 read per-kb from LDS
        float v = 0.f;
        #pragma unroll
        for (int kb = 0; kb < 4; ++kb) {
            f32x4 w2k = *(const f32x4*)(swg + 64 + kb * 16);
            #pragma unroll
            for (int r = 0; r < 4; ++r)
                v += w2k[r] * fmaxf(acc1[kb][r], 0.f);
        }
        v += __shfl_xor(v, 16);
        v += __shfl_xor(v, 32);
        if (lane < 16)
            out[(size_t)m * HW + pxg0 + s * 16 + lane] = v + (sw[128] - 2.19f);
    }
}

extern "C" void kernel_launch(void* const* d_in, const int* in_sizes, int n_in,
                              void* d_out, int out_size, void* d_ws, size_t ws_size,
                              hipStream_t stream) {
    const float* x      = (const float*)d_in[0];
    const float* params = (const float*)d_in[1];
    float* out          = (float*)d_out;

    const int N = in_sizes[0] / (64 * HW);   // 4
    const int M = in_sizes[1] / NPARAM;      // 32
    const int num_ins = M / N;               // 8

    pack_weights<<<dim3(M, 2), 256, 0, stream>>>(params, (unsigned*)d_ws);

    dim3 grid(HW / 128, N);                  // 125 x 4 = 500 blocks
    condlane_reg<<<grid, 512, 37120, stream>>>(x, (const unsigned*)d_ws, out, num_ins);
}

// Round 17
// 28.762 us; speedup vs baseline: 2.2223x; 1.0007x over previous
//
#include <hip/hip_runtime.h>

typedef __attribute__((ext_vector_type(8)))  short    short8;   // 8 bf16 (K=32 A/B frag)
typedef __attribute__((ext_vector_type(4)))  short    s16x4;    // 4 bf16 (K=16 A/B frag)
typedef __attribute__((ext_vector_type(4)))  float    f32x4;    // 16x16 C/D frag
typedef __attribute__((ext_vector_type(4)))  unsigned uint4_;
typedef __attribute__((ext_vector_type(2)))  unsigned uint2_;

#define HW     16000
#define WWID   200
#define NPARAM 8513
// raw param offsets: w0[64][66] @0, w1[64][64] @4224, w2 @8320, b0 @8384, b1 @8448, b2 @8512
// packed ws per instance (dwords, stride 4864 = 19456 B):
//   w0 x-cols K=32 A-frags [0,2048): 8 frags (ch*4+kb) x 256 dw
//   w1 K=16 A-frags [2048,4096): 16 frags (kb*4+ks) x 128 dw
//   loc K=16 A-frags [4096,4608): 4 frags (kb) x 128 dw; row k: g==0 -> {w00,w01,b0,0}, else 0
//   b1 f32 @4608(64), w2 f32 @4672(64), b2 @4736
#define PACK_STRIDE 4864

__device__ __forceinline__ unsigned pkbf2(float a, float b) {   // 1 VALU op (RNE)
    unsigned r;
    asm("v_cvt_pk_bf16_f32 %0, %1, %2" : "=v"(r) : "v"(a), "v"(b));
    return r;
}
__device__ __forceinline__ s16x4 mk4(unsigned a, unsigned b) {
    uint2_ u; u.x = a; u.y = b;
    return __builtin_bit_cast(s16x4, u);
}
// K=16 bf16 MFMA via inline asm; s_nop 2 covers VALU-write -> MFMA-read wait
// states (R10 lesson). Use ONLY when SrcC comes from VALU/ds_read/same-type asm.
__device__ __forceinline__ void mfma16(f32x4& acc, s16x4 a, s16x4 b) {
    asm("s_nop 2\n\tv_mfma_f32_16x16x16_bf16 %0, %1, %2, %0"
        : "+v"(acc) : "v"(a), "v"(b));
}
// Variant for SrcC written by a BUILTIN (cross-type) MFMA: the compiler cannot
// see through the asm, and MFMA->MFMA SrcC cross-type needs more wait states
// (R16's 0.906 absmax failure). s_nop 7 = 8 waits > any documented requirement.
__device__ __forceinline__ void mfma16c(f32x4& acc, s16x4 a, s16x4 b) {
    asm("s_nop 7\n\tv_mfma_f32_16x16x16_bf16 %0, %1, %2, %0"
        : "+v"(acc) : "v"(a), "v"(b));
}

// grid (M, 2) x 256 thr. y=0: w0 x-frags + loc frags + smalls; y=1: w1 frags.
__global__ __launch_bounds__(256) void pack_weights(
    const float* __restrict__ params, unsigned* __restrict__ wp)
{
    const int m   = blockIdx.x;
    const int tid = threadIdx.x;
    const float* pm = params + (size_t)m * NPARAM;
    unsigned* dst = wp + (size_t)m * PACK_STRIDE;

    if (blockIdx.y == 0) {
        const int l  = tid >> 2;
        const int i0 = (tid & 3) * 2;
        #pragma unroll
        for (int f = 0; f < 8; ++f) {                  // w0 x-cols, K=64 (ch*4+kb)
            int ch = f >> 2, kb = f & 3;
            int k = kb * 16 + (l & 15);
            int c = ch * 32 + (l >> 4) * 8 + i0;       // x-channel 0..63
            const float* s = pm + k * 66 + 2 + c;
            dst[f * 256 + tid] = pkbf2(s[0], s[1]);
        }
        #pragma unroll
        for (int it = 0; it < 2; ++it) {               // loc frags: 512 dw
            int idx = it * 256 + tid;
            int kb = idx >> 7, rem = idx & 127;
            int ll = rem >> 1, d = rem & 1;
            int gg = (ll >> 4) & 3;
            int k = kb * 16 + (ll & 15);
            unsigned v = 0u;
            if (gg == 0)
                v = d ? pkbf2(pm[8384 + k], 0.f)       // {b0, 0}
                      : pkbf2(pm[k * 66 + 0], pm[k * 66 + 1]);  // {w00, w01}
            dst[4096 + idx] = v;
        }
        float* fd = (float*)dst;
        if (tid < 64) {
            fd[4608 + tid] = pm[8448 + tid];           // b1
            fd[4672 + tid] = pm[8320 + tid];           // w2
        }
        if (tid == 0) fd[4736] = pm[8512];             // b2
    } else {
        #pragma unroll
        for (int i = tid; i < 2048; i += 256) {        // w1 K=16 A-frags
            int f = i >> 7, r = i & 127;
            int l = r >> 1, d = i & 1;
            int kb = f >> 2, ks = f & 3;
            int row = kb * 16 + (l & 15);
            int col = ks * 16 + (l >> 4) * 4 + d * 2;
            const float* s = pm + 4224 + row * 64 + col;
            dst[2048 + i] = pkbf2(s[0], s[1]);
        }
    }
}

// block = 512 thr (8 waves); wave wid owns FULL instance m = n*num_ins+wid over
// a 128-px tile (8 slices). Grid 125 x N = 500 -> 2 blocks/CU.
// Register diet: loc/bias via K=16 mfma (8 regs A, B from 2-reg col/row
// counters); xt 64ch only (16KB); b1/w2/b2 in wave-private LDS.
// Peak live ~116 < 128 hard occupancy step -> 4 waves/SIMD.
__global__ __launch_bounds__(512, 4) void condlane_reg(
    const float* __restrict__ x,        // [N, 64, HW]
    const unsigned* __restrict__ wp,    // packed weights
    float* __restrict__ out,            // [M, HW]
    int num_ins)
{
    extern __shared__ char lds_[];
    char*  xt = lds_;                   // 16384 B: [128 px][64 ch] bf16, swz (p&7)<<4
    float* sm = (float*)(lds_ + 16384); // [8 waves][136 f32]: b1(64), w2(64), b2
    const int tid  = threadIdx.x;
    const int lane = tid & 63;
    const int wid  = tid >> 6;
    const int n    = blockIdx.y;
    const int pxg0 = blockIdx.x * 128;  // 125*128 == HW exactly
    const int g    = (lane >> 4) & 3;
    const int px16 = lane & 15;

    // ---- stage x tile: [128 px][64 ch] bf16, swizzle byte ^= (p&7)<<4 ----
    {
        const int p   = tid & 127;
        const int sel = tid >> 7;       // 0..3, 16 fp32 channels each
        const float* xp = x + (size_t)n * 64 * HW + (pxg0 + p);
        #pragma unroll
        for (int it = 0; it < 2; ++it) {
            int c0 = sel * 16 + it * 8;
            uint4_ d;
            d.x = pkbf2(xp[(size_t)(c0 + 0) * HW], xp[(size_t)(c0 + 1) * HW]);
            d.y = pkbf2(xp[(size_t)(c0 + 2) * HW], xp[(size_t)(c0 + 3) * HW]);
            d.z = pkbf2(xp[(size_t)(c0 + 4) * HW], xp[(size_t)(c0 + 5) * HW]);
            d.w = pkbf2(xp[(size_t)(c0 + 6) * HW], xp[(size_t)(c0 + 7) * HW]);
            *(uint4_*)(xt + ((p * 128 + c0 * 2) ^ ((p & 7) << 4))) = d;
        }
    }

    // ---- wave-resident weights (coalesced from packed image) + LDS smalls ----
    const int m = n * num_ins + wid;    // 8 waves == num_ins
    const unsigned* wm = wp + (size_t)m * PACK_STRIDE;
    const float*    fm = (const float*)wm;
    float* sw = sm + wid * 136;         // this wave's smalls (wave-private)

    sw[lane]      = fm[4608 + lane];    // b1
    sw[64 + lane] = fm[4672 + lane];    // w2
    if (lane == 0) sw[128] = fm[4736];  // b2

    short8 w0f[2][4];                   // 32 VGPR
    s16x4  w1f4[4][4];                  // 32 VGPR
    s16x4  wloc[4];                     // 8 VGPR
    #pragma unroll
    for (int ch = 0; ch < 2; ++ch)
        #pragma unroll
        for (int kb = 0; kb < 4; ++kb)
            w0f[ch][kb] = *(const short8*)(wm + (ch * 4 + kb) * 256 + lane * 4);
    #pragma unroll
    for (int kb = 0; kb < 4; ++kb) {
        #pragma unroll
        for (int ks = 0; ks < 4; ++ks)
            w1f4[kb][ks] = *(const s16x4*)(wm + 2048 + (kb * 4 + ks) * 128 + lane * 2);
        wloc[kb] = *(const s16x4*)(wm + 4096 + kb * 128 + lane * 2);
    }

    // loc B-frag state: col/row counters for this lane's pixel track
    const int pxg00 = pxg0 + px16;
    float colf = (float)(pxg00 % WWID);
    float rowf = (float)(pxg00 / WWID);
    const unsigned gmask = (g == 0) ? 0xFFFFFFFFu : 0u;
    const unsigned lbv   = (g == 0) ? 0x00003f80u : 0u;   // bf16{1, 0}

    __syncthreads();                    // xt ready — the only barrier

    const int swz = (px16 & 7) << 4;
    const float* swg = sw + g * 4;

    for (int s = 0; s < 8; ++s) {
        const int pxl = s * 16 + px16;
        short8 xf[2];
        #pragma unroll
        for (int ch = 0; ch < 2; ++ch)
            xf[ch] = *(const short8*)(xt + ((pxl * 128 + ch * 64 + g * 16) ^ swz));
        // layer 0: 8 builtin MFMA (K=64 x-part), zero-C init on first
        f32x4 zero4; zero4[0] = 0.f; zero4[1] = 0.f; zero4[2] = 0.f; zero4[3] = 0.f;
        f32x4 acc0[4];
        #pragma unroll
        for (int kb = 0; kb < 4; ++kb)
            acc0[kb] = __builtin_amdgcn_mfma_f32_16x16x32_bf16(w0f[0][kb], xf[0], zero4, 0, 0, 0);
        #pragma unroll
        for (int kb = 0; kb < 4; ++kb)
            acc0[kb] = __builtin_amdgcn_mfma_f32_16x16x32_bf16(w0f[1][kb], xf[1], acc0[kb], 0, 0, 0);
        // + loc/bias via K=16 mfma: B = {lx, ly, 1, 0}. SrcC was written by a
        // BUILTIN MFMA -> use the long-nop variant (R16 failure fix).
        {
            float lx = colf * (1.0f / WWID);
            float ly = rowf * (1.0f / WWID);   // source bug: also /W
            s16x4 locB = mk4(pkbf2(lx, ly) & gmask, lbv);
            #pragma unroll
            for (int kb = 0; kb < 4; ++kb)
                mfma16c(acc0[kb], wloc[kb], locB);
            // advance col/row (wrap at WWID)
            colf += 16.f;
            bool wrap = colf >= (float)WWID;
            colf = wrap ? colf - (float)WWID : colf;
            rowf = wrap ? rowf + 1.f : rowf;
        }
        // hazard: asm-MFMA write -> VALU read (nops tied to acc0)
        asm("s_nop 7\n\ts_nop 7"
            : "+v"(acc0[0]), "+v"(acc0[1]), "+v"(acc0[2]), "+v"(acc0[3]));
        // relu -> bf16 in registers: acc0[ks] IS L1's B-frag for chunk ks
        s16x4 hf[4];
        #pragma unroll
        for (int ks = 0; ks < 4; ++ks)
            hf[ks] = mk4(pkbf2(fmaxf(acc0[ks][0], 0.f), fmaxf(acc0[ks][1], 0.f)),
                         pkbf2(fmaxf(acc0[ks][2], 0.f), fmaxf(acc0[ks][3], 0.f)));
        // layer 1: acc1 init = ds_read of b1 (lgkmcnt-tracked); 16 x K=16 asm MFMA
        f32x4 acc1[4];
        #pragma unroll
        for (int kb = 0; kb < 4; ++kb)
            acc1[kb] = *(const f32x4*)(swg + kb * 16);
        #pragma unroll
        for (int ks = 0; ks < 4; ++ks)
            #pragma unroll
            for (int kb = 0; kb < 4; ++kb)
                mfma16(acc1[kb], w1f4[kb][ks], hf[ks]);
        // exit hazard: MFMA write -> VALU read
        asm("s_nop 7\n\ts_nop 7"
            : "+v"(acc1[0]), "+v"(acc1[1]), "+v"(acc1[2]), "+v"(acc1[3]));
        // layer 2: 64->1 fp32 VALU, w2 from LDS
        float v = 0.f;
        #pragma unroll
        for (int kb = 0; kb < 4; ++kb) {
            f32x4 w2k = *(const f32x4*)(swg + 64 + kb * 16);
            #pragma unroll
            for (int r = 0; r < 4; ++r)
                v += w2k[r] * fmaxf(acc1[kb][r], 0.f);
        }
        v += __shfl_xor(v, 16);
        v += __shfl_xor(v, 32);
        if (lane < 16)
            out[(size_t)m * HW + pxg0 + s * 16 + lane] = v + (sw[128] - 2.19f);
    }
}

extern "C" void kernel_launch(void* const* d_in, const int* in_sizes, int n_in,
                              void* d_out, int out_size, void* d_ws, size_t ws_size,
                              hipStream_t stream) {
    const float* x      = (const float*)d_in[0];
    const float* params = (const float*)d_in[1];
    float* out          = (float*)d_out;

    const int N = in_sizes[0] / (64 * HW);   // 4
    const int M = in_sizes[1] / NPARAM;      // 32
    const int num_ins = M / N;               // 8

    pack_weights<<<dim3(M, 2), 256, 0, stream>>>(params, (unsigned*)d_ws);

    dim3 grid(HW / 128, N);                  // 125 x 4 = 500 blocks
    condlane_reg<<<grid, 512, 20736, stream>>>(x, (const unsigned*)d_ws, out, num_ins);
}

// Round 18
// 26.715 us; speedup vs baseline: 2.3926x; 1.0766x over previous
//
#include <hip/hip_runtime.h>

typedef __attribute__((ext_vector_type(8)))  short    short8;   // 8 bf16 (K=32 A/B frag)
typedef __attribute__((ext_vector_type(4)))  short    s16x4;    // 4 bf16 (K=16 A/B frag)
typedef __attribute__((ext_vector_type(4)))  float    f32x4;    // 16x16 C/D frag
typedef __attribute__((ext_vector_type(4)))  unsigned uint4_;
typedef __attribute__((ext_vector_type(2)))  unsigned uint2_;

#define HW     16000
#define WWID   200
#define NPARAM 8513
// raw param offsets: w0[64][66] @0, w1[64][64] @4224, w2 @8320, b0 @8384, b1 @8448, b2 @8512
// packed ws per instance (dwords, stride 6144 = 24KB):
//   w0 K=32 A-frags [0,3072): 12 frags (ch*4+kb) x 256 dw
//   w1 K=16 A-frags [3072,5120): 16 frags (kb*4+ks) x 128 dw
//   b1 f32 @5120(64), w2 f32 @5184(64), b2 @5248
#define PACK_STRIDE 6144

__device__ __forceinline__ unsigned pkbf2(float a, float b) {   // 1 VALU op (RNE)
    unsigned r;
    asm("v_cvt_pk_bf16_f32 %0, %1, %2" : "=v"(r) : "v"(a), "v"(b));
    return r;
}
__device__ __forceinline__ s16x4 mk4(unsigned a, unsigned b) {
    uint2_ u; u.x = a; u.y = b;
    return __builtin_bit_cast(s16x4, u);
}

// L0 K-channel map: 0..63 -> x (w0 col c+2); 64 -> lx; 65 -> ly; 66 -> 1*b0; 67..95 -> 0
__device__ __forceinline__ float w0val(const float* pm, int k, int c) {
    if (c < 64)  return pm[k * 66 + c + 2];
    if (c == 64) return pm[k * 66 + 0];
    if (c == 65) return pm[k * 66 + 1];
    if (c == 66) return pm[8384 + k];
    return 0.0f;
}

// grid (M, 2) x 256 thr. y=0: w0 frags + smalls; y=1: w1 K=16 frags.
__global__ __launch_bounds__(256) void pack_weights(
    const float* __restrict__ params, unsigned* __restrict__ wp)
{
    const int m   = blockIdx.x;
    const int tid = threadIdx.x;
    const float* pm = params + (size_t)m * NPARAM;
    unsigned* dst = wp + (size_t)m * PACK_STRIDE;

    if (blockIdx.y == 0) {
        const int l  = tid >> 2;
        const int i0 = (tid & 3) * 2;
        #pragma unroll
        for (int frag = 0; frag < 12; ++frag) {        // w0, K=96 (ch*4+kb)
            int ch = frag >> 2, kb = frag & 3;
            int k = kb * 16 + (l & 15);
            int c = ch * 32 + (l >> 4) * 8 + i0;
            dst[frag * 256 + tid] = pkbf2(w0val(pm, k, c), w0val(pm, k, c + 1));
        }
        float* fd = (float*)dst;
        if (tid < 64) {
            fd[5120 + tid] = pm[8448 + tid];           // b1
            fd[5184 + tid] = pm[8320 + tid];           // w2
        }
        if (tid == 0) fd[5248] = pm[8512];             // b2
    } else {
        #pragma unroll
        for (int i = tid; i < 2048; i += 256) {        // w1 K=16 A-frags
            int f = i >> 7, r = i & 127;
            int l = r >> 1, d = i & 1;
            int kb = f >> 2, ks = f & 3;
            int row = kb * 16 + (l & 15);
            int col = ks * 16 + (l >> 4) * 4 + d * 2;
            const float* s = pm + 4224 + row * 64 + col;
            dst[3072 + i] = pkbf2(s[0], s[1]);
        }
    }
}

// block = 512 thr (8 waves); wave wid owns FULL instance m = n*num_ins+wid.
// R12 base + chain shortening: (1) L1 = ONE asm block (single s_nop 2, 16
// MFMAs, ks-major so 4 acc chains interleave); (2) L2 = 4 K=16 MFMAs with
// w2 as a row-0-only A-frag (C/D<->B identity again) -> no fp32 epilogue,
// no cross-lane shuffles. h0 and h1 both stay in registers.
__global__ __launch_bounds__(512, 2) void condlane_reg(
    const float* __restrict__ x,        // [N, 64, HW]
    const unsigned* __restrict__ wp,    // packed weights
    float* __restrict__ out,            // [M, HW]
    int num_ins)
{
    extern __shared__ char lds_[];
    char* xt = lds_;                    // 65536 B
    const int tid  = threadIdx.x;
    const int lane = tid & 63;
    const int wid  = tid >> 6;
    const int n    = blockIdx.y;
    const int pxg0 = blockIdx.x * 256;
    const int g    = (lane >> 4) & 3;
    const int px16 = lane & 15;

    // ---- stage x tile: [256 px][128 ch] bf16, swizzle byte ^= (p&15)<<4 ----
    {
        const int p   = tid & 255;
        const int sel = tid >> 8;       // 0..1, 32 fp32 channels each
        const int pc  = min(pxg0 + p, HW - 1);
        const float* xp = x + (size_t)n * 64 * HW + pc;
        #pragma unroll
        for (int it = 0; it < 4; ++it) {
            int c0 = sel * 32 + it * 8;
            uint4_ d;
            d.x = pkbf2(xp[(size_t)(c0 + 0) * HW], xp[(size_t)(c0 + 1) * HW]);
            d.y = pkbf2(xp[(size_t)(c0 + 2) * HW], xp[(size_t)(c0 + 3) * HW]);
            d.z = pkbf2(xp[(size_t)(c0 + 4) * HW], xp[(size_t)(c0 + 5) * HW]);
            d.w = pkbf2(xp[(size_t)(c0 + 6) * HW], xp[(size_t)(c0 + 7) * HW]);
            *(uint4_*)(xt + ((p * 256 + c0 * 2) ^ ((p & 15) << 4))) = d;
        }
        // const K-channels 64..95 = {lx, ly, 1, 0 ...}
        const int pg = pxg0 + p;        // values for pg>=HW never consumed
        float lx = (float)(pg % WWID) * (1.0f / WWID);
        float ly = (float)(pg / WWID) * (1.0f / WWID);   // source bug: also /W
        uint4_ z;  z.x = 0; z.y = 0; z.z = 0; z.w = 0;
        uint4_ cv; cv.x = pkbf2(lx, ly); cv.y = pkbf2(1.f, 0.f); cv.z = 0; cv.w = 0;
        int ba = (p * 256 + 128 + sel * 32) ^ ((p & 15) << 4);
        int bb = (p * 256 + 144 + sel * 32) ^ ((p & 15) << 4);
        *(uint4_*)(xt + ba) = (sel == 0) ? cv : z;
        *(uint4_*)(xt + bb) = z;
    }

    // ---- wave-resident weights: coalesced loads from packed image ----
    const int m = n * num_ins + wid;    // 8 waves == num_ins
    const unsigned* wm = wp + (size_t)m * PACK_STRIDE;

    short8 w0f[3][4];
    s16x4  w1f[4][4];
    #pragma unroll
    for (int ch = 0; ch < 3; ++ch)
        #pragma unroll
        for (int kb = 0; kb < 4; ++kb)
            w0f[ch][kb] = *(const short8*)(wm + (ch * 4 + kb) * 256 + lane * 4);
    #pragma unroll
    for (int kb = 0; kb < 4; ++kb)
        #pragma unroll
        for (int ks = 0; ks < 4; ++ks)
            w1f[kb][ks] = *(const s16x4*)(wm + 3072 + (kb * 4 + ks) * 128 + lane * 2);
    const float* fm = (const float*)wm;
    f32x4 bias1[4];
    s16x4 w2A[4];                       // L2 A-frag: w2 on row 0 only
    #pragma unroll
    for (int kb = 0; kb < 4; ++kb) {
        bias1[kb] = *(const f32x4*)(fm + 5120 + kb * 16 + g * 4);
        unsigned lo = 0u, hi = 0u;
        if (px16 == 0) {
            const float* w2p = fm + 5184 + kb * 16 + g * 4;
            lo = pkbf2(w2p[0], w2p[1]);
            hi = pkbf2(w2p[2], w2p[3]);
        }
        w2A[kb] = mk4(lo, hi);
    }
    const float b2 = fm[5248] - 2.19f;

    __syncthreads();                    // xt ready — the only barrier

    const int swz = px16 << 4;
    const int nsl = min(16, (HW - pxg0) >> 4);
    f32x4 zero4; zero4[0] = 0.f; zero4[1] = 0.f; zero4[2] = 0.f; zero4[3] = 0.f;

    for (int s = 0; s < 16; ++s) {
        const int pxl = s * 16 + px16;
        short8 xf[3];
        #pragma unroll
        for (int ch = 0; ch < 3; ++ch)
            xf[ch] = *(const short8*)(xt + ((pxl * 256 + ch * 64 + g * 16) ^ swz));
        // layer 0: 12 builtin MFMA (K=96), zero-C init on first ch
        f32x4 acc0[4];
        #pragma unroll
        for (int kb = 0; kb < 4; ++kb)
            acc0[kb] = __builtin_amdgcn_mfma_f32_16x16x32_bf16(w0f[0][kb], xf[0], zero4, 0, 0, 0);
        #pragma unroll
        for (int ch = 1; ch < 3; ++ch)
            #pragma unroll
            for (int kb = 0; kb < 4; ++kb)
                acc0[kb] = __builtin_amdgcn_mfma_f32_16x16x32_bf16(w0f[ch][kb], xf[ch], acc0[kb], 0, 0, 0);
        // relu -> bf16 in regs: acc0[ks] IS L1's B-frag for chunk ks
        s16x4 hf[4];
        #pragma unroll
        for (int ks = 0; ks < 4; ++ks)
            hf[ks] = mk4(pkbf2(fmaxf(acc0[ks][0], 0.f), fmaxf(acc0[ks][1], 0.f)),
                         pkbf2(fmaxf(acc0[ks][2], 0.f), fmaxf(acc0[ks][3], 0.f)));
        // layer 1: ONE asm block, single s_nop 2 (VALU->MFMA guard), 16 MFMAs
        // ks-major: consecutive ops hit different accs (4 interleaved chains);
        // same-acc accumulate reuse is HW-interlocked (R11-proven).
        f32x4 acc1[4];
        #pragma unroll
        for (int kb = 0; kb < 4; ++kb) acc1[kb] = bias1[kb];
        asm("s_nop 2\n\t"
            "v_mfma_f32_16x16x16_bf16 %0, %4, %20, %0\n\t"
            "v_mfma_f32_16x16x16_bf16 %1, %5, %20, %1\n\t"
            "v_mfma_f32_16x16x16_bf16 %2, %6, %20, %2\n\t"
            "v_mfma_f32_16x16x16_bf16 %3, %7, %20, %3\n\t"
            "v_mfma_f32_16x16x16_bf16 %0, %8, %21, %0\n\t"
            "v_mfma_f32_16x16x16_bf16 %1, %9, %21, %1\n\t"
            "v_mfma_f32_16x16x16_bf16 %2, %10, %21, %2\n\t"
            "v_mfma_f32_16x16x16_bf16 %3, %11, %21, %3\n\t"
            "v_mfma_f32_16x16x16_bf16 %0, %12, %22, %0\n\t"
            "v_mfma_f32_16x16x16_bf16 %1, %13, %22, %1\n\t"
            "v_mfma_f32_16x16x16_bf16 %2, %14, %22, %2\n\t"
            "v_mfma_f32_16x16x16_bf16 %3, %15, %22, %3\n\t"
            "v_mfma_f32_16x16x16_bf16 %0, %16, %23, %0\n\t"
            "v_mfma_f32_16x16x16_bf16 %1, %17, %23, %1\n\t"
            "v_mfma_f32_16x16x16_bf16 %2, %18, %23, %2\n\t"
            "v_mfma_f32_16x16x16_bf16 %3, %19, %23, %3"
            : "+v"(acc1[0]), "+v"(acc1[1]), "+v"(acc1[2]), "+v"(acc1[3])
            : "v"(w1f[0][0]), "v"(w1f[1][0]), "v"(w1f[2][0]), "v"(w1f[3][0]),
              "v"(w1f[0][1]), "v"(w1f[1][1]), "v"(w1f[2][1]), "v"(w1f[3][1]),
              "v"(w1f[0][2]), "v"(w1f[1][2]), "v"(w1f[2][2]), "v"(w1f[3][2]),
              "v"(w1f[0][3]), "v"(w1f[1][3]), "v"(w1f[2][3]), "v"(w1f[3][3]),
              "v"(hf[0]), "v"(hf[1]), "v"(hf[2]), "v"(hf[3]));
        // exit hazard: asm-MFMA write -> VALU read (nops tied to accs)
        asm("s_nop 7\n\ts_nop 7"
            : "+v"(acc1[0]), "+v"(acc1[1]), "+v"(acc1[2]), "+v"(acc1[3]));
        // layer 2 as MFMA: relu(acc1[kb]) packed IS the B-frag; A = w2 (row 0).
        s16x4 hg[4];
        #pragma unroll
        for (int kb = 0; kb < 4; ++kb)
            hg[kb] = mk4(pkbf2(fmaxf(acc1[kb][0], 0.f), fmaxf(acc1[kb][1], 0.f)),
                         pkbf2(fmaxf(acc1[kb][2], 0.f), fmaxf(acc1[kb][3], 0.f)));
        f32x4 acc2 = zero4;
        asm("s_nop 2\n\t"
            "v_mfma_f32_16x16x16_bf16 %0, %1, %5, %0\n\t"
            "v_mfma_f32_16x16x16_bf16 %0, %2, %6, %0\n\t"
            "v_mfma_f32_16x16x16_bf16 %0, %3, %7, %0\n\t"
            "v_mfma_f32_16x16x16_bf16 %0, %4, %8, %0"
            : "+v"(acc2)
            : "v"(w2A[0]), "v"(w2A[1]), "v"(w2A[2]), "v"(w2A[3]),
              "v"(hg[0]), "v"(hg[1]), "v"(hg[2]), "v"(hg[3]));
        asm("s_nop 7\n\ts_nop 7" : "+v"(acc2));
        // row 0 of D = out[px]; lives in reg 0 of lanes g==0 (lanes 0..15)
        if (lane < 16 && s < nsl)
            out[(size_t)m * HW + pxg0 + s * 16 + lane] = acc2[0] + b2;
    }
}

extern "C" void kernel_launch(void* const* d_in, const int* in_sizes, int n_in,
                              void* d_out, int out_size, void* d_ws, size_t ws_size,
                              hipStream_t stream) {
    const float* x      = (const float*)d_in[0];
    const float* params = (const float*)d_in[1];
    float* out          = (float*)d_out;

    const int N = in_sizes[0] / (64 * HW);   // 4
    const int M = in_sizes[1] / NPARAM;      // 32
    const int num_ins = M / N;               // 8

    pack_weights<<<dim3(M, 2), 256, 0, stream>>>(params, (unsigned*)d_ws);

    dim3 grid((HW + 255) / 256, N);          // 63 x 4 = 252 blocks
    condlane_reg<<<grid, 512, 65536, stream>>>(x, (const unsigned*)d_ws, out, num_ins);
}

// Round 19
// 26.292 us; speedup vs baseline: 2.4312x; 1.0161x over previous
//
#include <hip/hip_runtime.h>

typedef __attribute__((ext_vector_type(8)))  short    short8;   // 8 bf16 (K=32 A/B frag)
typedef __attribute__((ext_vector_type(4)))  short    s16x4;    // 4 bf16 (K=16 A/B frag)
typedef __attribute__((ext_vector_type(4)))  float    f32x4;    // 16x16 C/D frag
typedef __attribute__((ext_vector_type(4)))  unsigned uint4_;
typedef __attribute__((ext_vector_type(2)))  unsigned uint2_;

#define HW     16000
#define WWID   200
#define NPARAM 8513
// raw param offsets: w0[64][66] @0, w1[64][64] @4224, w2 @8320, b0 @8384, b1 @8448, b2 @8512

__device__ __forceinline__ unsigned pkbf2(float a, float b) {   // 1 VALU op (RNE)
    unsigned r;
    asm("v_cvt_pk_bf16_f32 %0, %1, %2" : "=v"(r) : "v"(a), "v"(b));
    return r;
}
__device__ __forceinline__ short8 mk8(unsigned a, unsigned b, unsigned c, unsigned d) {
    uint4_ u; u.x = a; u.y = b; u.z = c; u.w = d;
    return __builtin_bit_cast(short8, u);
}
__device__ __forceinline__ s16x4 mk4(unsigned a, unsigned b) {
    uint2_ u; u.x = a; u.y = b;
    return __builtin_bit_cast(s16x4, u);
}
// K=16 bf16 MFMA via inline asm. The leading s_nop 2 covers the CDNA
// "VALU write -> MFMA read SrcA/B/C" manually-inserted-wait-state hazard that
// the compiler's hazard recognizer cannot see through inline asm.
__device__ __forceinline__ void mfma16(f32x4& acc, s16x4 a, s16x4 b) {
    asm("s_nop 2\n\tv_mfma_f32_16x16x16_bf16 %0, %1, %2, %0"
        : "+v"(acc) : "v"(a), "v"(b));
}

// block = 512 threads (8 waves); wave wid owns FULL instance m = n*num_ins+wid.
// relu(acc0[ks]) packed to bf16 IS L1's B operand for K-chunk ks (layout
// identity): h0 never touches LDS; slice loop has no barriers/shuffles/LDS-wr.
// LDS: xt [256 px][128 ch] bf16 XOR-swizzled (64KB) only. One barrier total.
__global__ __launch_bounds__(512, 2) void condlane_reg(
    const float* __restrict__ x,        // [N, 64, HW]
    const float* __restrict__ params,   // [M, 8513]
    float* __restrict__ out,            // [M, HW]
    int num_ins)
{
    extern __shared__ char lds_[];
    char* xt = lds_;                    // 65536 B
    const int tid  = threadIdx.x;
    const int lane = tid & 63;
    const int wid  = tid >> 6;
    const int n    = blockIdx.y;
    const int pxg0 = blockIdx.x * 256;
    const int g    = (lane >> 4) & 3;
    const int px16 = lane & 15;

    // ---- stage x tile: [256 px][128 ch] bf16, swizzle byte ^= (p&15)<<4 ----
    {
        const int p   = tid & 255;
        const int sel = tid >> 8;       // 0..1, 32 fp32 channels each
        const int pc  = min(pxg0 + p, HW - 1);
        const float* xp = x + (size_t)n * 64 * HW + pc;
        #pragma unroll
        for (int it = 0; it < 4; ++it) {
            int c0 = sel * 32 + it * 8;
            uint4_ d;
            d.x = pkbf2(xp[(size_t)(c0 + 0) * HW], xp[(size_t)(c0 + 1) * HW]);
            d.y = pkbf2(xp[(size_t)(c0 + 2) * HW], xp[(size_t)(c0 + 3) * HW]);
            d.z = pkbf2(xp[(size_t)(c0 + 4) * HW], xp[(size_t)(c0 + 5) * HW]);
            d.w = pkbf2(xp[(size_t)(c0 + 6) * HW], xp[(size_t)(c0 + 7) * HW]);
            *(uint4_*)(xt + ((p * 256 + c0 * 2) ^ ((p & 15) << 4))) = d;
        }
        // const K-channels 64..95 = {lx, ly, 1, 0 ...}
        const int pg = pxg0 + p;        // values for pg>=HW never consumed
        float lx = (float)(pg % WWID) * (1.0f / WWID);
        float ly = (float)(pg / WWID) * (1.0f / WWID);   // source bug: also /W
        uint4_ z;  z.x = 0; z.y = 0; z.z = 0; z.w = 0;
        uint4_ cv; cv.x = pkbf2(lx, ly); cv.y = pkbf2(1.f, 0.f); cv.z = 0; cv.w = 0;
        int ba = (p * 256 + 128 + sel * 32) ^ ((p & 15) << 4);
        int bb = (p * 256 + 144 + sel * 32) ^ ((p & 15) << 4);
        *(uint4_*)(xt + ba) = (sel == 0) ? cv : z;
        *(uint4_*)(xt + bb) = z;
    }

    // ---- per-wave full-instance weight gather into register fragments ----
    const int m = n * num_ins + wid;    // 8 waves == num_ins
    const float* pm = params + (size_t)m * NPARAM;

    short8 w0f[3][4];                   // L0: K=96 frags (x32 shape)
    s16x4  w1f4[4][4];                  // L1: [kb out-block][ks K-chunk] (x16 shape)
    #pragma unroll
    for (int kb = 0; kb < 4; ++kb) {
        const int k = kb * 16 + px16;   // A-frag row = lane&15
        #pragma unroll
        for (int ch = 0; ch < 2; ++ch) {
            const float* s0 = pm + k * 66 + 2 + ch * 32 + g * 8;  // w0 x-cols
            w0f[ch][kb] = mk8(pkbf2(s0[0], s0[1]), pkbf2(s0[2], s0[3]),
                              pkbf2(s0[4], s0[5]), pkbf2(s0[6], s0[7]));
        }
        // K-channels 64..95 = {lx, ly, 1, 0...} -> cols {w00, w01, b0, 0...}
        float a = (g == 0) ? pm[k * 66 + 0] : 0.f;
        float b = (g == 0) ? pm[k * 66 + 1] : 0.f;
        float c = (g == 0) ? pm[8384 + k]   : 0.f;
        w0f[2][kb] = mk8(pkbf2(a, b), pkbf2(c, 0.f), 0u, 0u);
        // w1 A-frag (x16 shape): row k2 = kb*16 + (lane&15), k = g*4 + j
        #pragma unroll
        for (int ks = 0; ks < 4; ++ks) {
            const float* s1 = pm + 4224 + (kb * 16 + px16) * 64 + ks * 16 + g * 4;
            w1f4[kb][ks] = mk4(pkbf2(s1[0], s1[1]), pkbf2(s1[2], s1[3]));
        }
    }
    f32x4 bias1[4], w2v[4];
    #pragma unroll
    for (int kb = 0; kb < 4; ++kb)
        #pragma unroll
        for (int r = 0; r < 4; ++r) {   // acc1[kb] reg r <-> k2 = kb*16 + g*4 + r
            bias1[kb][r] = pm[8448 + kb * 16 + g * 4 + r];
            w2v[kb][r]   = pm[8320 + kb * 16 + g * 4 + r];
        }
    const float b2 = pm[8512] - 2.19f;

    __syncthreads();                    // xt ready — the only barrier

    const int swz = px16 << 4;          // (pxl&15)<<4 == (lane&15)<<4 always
    const int nsl = min(16, (HW - pxg0) >> 4);

    for (int s = 0; s < 16; ++s) {
        const int pxl = s * 16 + px16;
        // x B-frags (K=96)
        short8 xf[3];
        #pragma unroll
        for (int ch = 0; ch < 3; ++ch)
            xf[ch] = *(const short8*)(xt + ((pxl * 256 + ch * 64 + g * 16) ^ swz));
        // layer 0: 12 MFMA (K=96), acc = 0 (loc+bias folded)
        f32x4 acc0[4];
        #pragma unroll
        for (int kb = 0; kb < 4; ++kb)
            #pragma unroll
            for (int j = 0; j < 4; ++j) acc0[kb][j] = 0.f;
        #pragma unroll
        for (int ch = 0; ch < 3; ++ch)
            #pragma unroll
            for (int kb = 0; kb < 4; ++kb)
                acc0[kb] = __builtin_amdgcn_mfma_f32_16x16x32_bf16(w0f[ch][kb], xf[ch], acc0[kb], 0, 0, 0);
        // relu -> bf16 IN REGISTERS: acc0[ks] becomes L1's B-frag for chunk ks
        s16x4 hf[4];
        #pragma unroll
        for (int ks = 0; ks < 4; ++ks)
            hf[ks] = mk4(pkbf2(fmaxf(acc0[ks][0], 0.f), fmaxf(acc0[ks][1], 0.f)),
                         pkbf2(fmaxf(acc0[ks][2], 0.f), fmaxf(acc0[ks][3], 0.f)));
        // layer 1: 16 x K=16 MFMA (inline asm, hazard-protected)
        f32x4 acc1[4];
        #pragma unroll
        for (int kb = 0; kb < 4; ++kb) acc1[kb] = bias1[kb];
        #pragma unroll
        for (int ks = 0; ks < 4; ++ks)
            #pragma unroll
            for (int kb = 0; kb < 4; ++kb)
                mfma16(acc1[kb], w1f4[kb][ks], hf[ks]);
        // exit hazard: MFMA write -> VALU read. Nops tied to the accs so the
        // following reads are data-ordered AFTER the wait.
        asm("s_nop 7\n\ts_nop 7"
            : "+v"(acc1[0]), "+v"(acc1[1]), "+v"(acc1[2]), "+v"(acc1[3]));
        // layer 2: 64->1 fp32 VALU + cross-group reduce
        float v = 0.f;
        #pragma unroll
        for (int kb = 0; kb < 4; ++kb)
            #pragma unroll
            for (int r = 0; r < 4; ++r)
                v += w2v[kb][r] * fmaxf(acc1[kb][r], 0.f);
        v += __shfl_xor(v, 16);
        v += __shfl_xor(v, 32);
        if (lane < 16 && s < nsl)
            out[(size_t)m * HW + pxg0 + s * 16 + lane] = v + b2;
    }
}

extern "C" void kernel_launch(void* const* d_in, const int* in_sizes, int n_in,
                              void* d_out, int out_size, void* d_ws, size_t ws_size,
                              hipStream_t stream) {
    const float* x      = (const float*)d_in[0];
    const float* params = (const float*)d_in[1];
    float* out          = (float*)d_out;

    const int N = in_sizes[0] / (64 * HW);   // 4
    const int M = in_sizes[1] / NPARAM;      // 32
    const int num_ins = M / N;               // 8

    dim3 grid((HW + 255) / 256, N);          // 63 x 4 = 252 blocks
    condlane_reg<<<grid, 512, 65536, stream>>>(x, params, out, num_ins);
}